// Round 1
// baseline (575.442 us; speedup 1.0000x reference)
//
#include <hip/hip_runtime.h>

// LatticeStyleConv: StyleGAN2-modulated 5-point stencil conv as implicit GEMM
// on bf16 MFMA (16x16x32). bs=8, ci=co=256, H=W=128.
//
// Kernel 1 (demod): d[b][o] = rsqrt(sum_{i,s} (w[o][i][s]*(y[b][i]+1))^2 + 1e-6)
// Kernel 2 (conv):  out[b,o,h,w] = sum_{i,s} w[o,i,s]*(y[b,i]+1)*d[b,o] * x[b,i,h+dh_s,w+dw_s]
//
// Block tile: 64 co x (4 rows x 64 cols). 4 waves; wave = one output row,
// Mw=64 x Nw=64 via 4x4 mfma tiles of 16x16, acc = 64 VGPR/lane.
// K-loop: 32 input channels/chunk.
//   x LDS tile: channel-PAIR interleaved bf16 [cp][row][col][2] so B-frags are
//               4x ds_read_b32 (pairplane stride padded to 412 ints for banking).
//   w LDS tile: A-frag-native [s][mt][quad][m][8] -> one ds_read_b128 per frag.
// Verified layouts (guide §3, m89/m91): A[m=lane&15][k=quad*8+j];
// C/D col=lane&15, row=quad*4+reg. B inferred symmetric: n=lane&15, k=quad*8+j.

typedef short v8s __attribute__((ext_vector_type(8)));
typedef float v4f __attribute__((ext_vector_type(4)));
typedef int   v4i __attribute__((ext_vector_type(4)));

#define BS 8
#define CI 256
#define CO 256
#define HH 128
#define WW 128

__device__ __forceinline__ unsigned short f2bf(float f) {
    unsigned u = __builtin_bit_cast(unsigned, f);
    u += 0x7FFFu + ((u >> 16) & 1u);   // round-to-nearest-even (inputs are finite)
    return (unsigned short)(u >> 16);
}

// ---------------- Kernel 1: demodulation factors ----------------
__global__ __launch_bounds__(256) void demod_kernel(const float* __restrict__ y,
                                                    const float* __restrict__ wgt,
                                                    float* __restrict__ dbuf) {
    const int bo = blockIdx.x;           // b*256 + o
    const int b = bo >> 8, o = bo & 255;
    const int i = threadIdx.x;           // one ci per thread
    const float* wp = wgt + (o * CI + i) * 5;
    const float ym = y[b * CI + i] + 1.0f;
    float s2 = 0.f;
    #pragma unroll
    for (int s = 0; s < 5; ++s) { float w = wp[s]; s2 += w * w; }
    float val = ym * ym * s2;
    #pragma unroll
    for (int off = 32; off > 0; off >>= 1) val += __shfl_down(val, off);
    __shared__ float red[4];
    if ((threadIdx.x & 63) == 0) red[threadIdx.x >> 6] = val;
    __syncthreads();
    if (threadIdx.x == 0) {
        float t = red[0] + red[1] + red[2] + red[3];
        dbuf[bo] = rsqrtf(t + 1e-6f);
    }
}

// ---------------- Kernel 2: modulated stencil conv (MFMA) ----------------
__global__ __launch_bounds__(256) void conv_kernel(const float* __restrict__ x,
                                                   const float* __restrict__ y,
                                                   const float* __restrict__ wgt,
                                                   const float* __restrict__ dbuf,
                                                   float* __restrict__ out) {
    const int b     = blockIdx.z;
    const int oBase = blockIdx.y * 64;
    const int st    = blockIdx.x;        // 0..63: 32 row-tiles x 2 col-tiles
    const int r0    = (st >> 1) * 4;
    const int c0    = (st & 1) * 64;

    const int tid  = threadIdx.x;
    const int wid  = tid >> 6;           // wave id 0..3 -> output row r0+wid
    const int lane = tid & 63;
    const int l15  = lane & 15;
    const int quad = lane >> 4;

    // x tile: 16 channel-pairs x 6 rows x 66 cols, stored as ints (2 bf16).
    // pairplane stride 412 ints (408 used + 4 pad -> quads hit disjoint banks)
    __shared__ int   xs4[16 * 412];                 // 26368 B
    __shared__ short wlds[5 * 4 * 4 * 16 * 8];      // 20480 B  [s][mt][q][m][j]

    v4f acc[4][4];
    #pragma unroll
    for (int a = 0; a < 4; ++a)
        #pragma unroll
        for (int n = 0; n < 4; ++n) acc[a][n] = (v4f){0.f, 0.f, 0.f, 0.f};

    const int row = r0 + wid;

    for (int ic0 = 0; ic0 < CI; ic0 += 32) {
        // ---- stage x: 16 pairs x 6 rows x 66 cols = 6336 packed ints ----
        for (int t = 0; t < 25; ++t) {
            int idx = tid + t * 256;
            if (idx < 6336) {
                int cp  = idx / 396;
                int rem = idx - cp * 396;
                int rr  = rem / 66;
                int cc  = rem - rr * 66;
                int gr  = r0 - 1 + rr;
                int gc  = c0 - 1 + cc;
                float v0 = 0.f, v1 = 0.f;
                if (gr >= 0 && gr < HH && gc >= 0 && gc < WW) {
                    const float* xp = x + ((size_t)(b * CI + ic0 + cp * 2) * HH + gr) * WW + gc;
                    v0 = xp[0];
                    v1 = xp[HH * WW];   // next channel, same pixel
                }
                unsigned pk = (unsigned)f2bf(v0) | ((unsigned)f2bf(v1) << 16);
                xs4[cp * 412 + rr * 68 + cc] = (int)pk;
            }
        }
        // ---- stage modulated weights: 64 o x 32 ci -> 2048 (o,i) pairs ----
        #pragma unroll
        for (int p = 0; p < 8; ++p) {
            int pidx = tid + p * 256;
            int ol = pidx >> 5;          // 0..63
            int il = pidx & 31;          // 0..31
            int o  = oBase + ol;
            int ci = ic0 + il;
            float scale = (y[b * CI + ci] + 1.0f) * dbuf[b * CO + o];
            const float* wp = wgt + (o * CI + ci) * 5;
            int base = (((ol >> 4) * 4 + (il >> 3)) * 16 + (ol & 15)) * 8 + (il & 7);
            #pragma unroll
            for (int s = 0; s < 5; ++s)
                wlds[base + s * (4 * 4 * 16 * 8)] = (short)f2bf(wp[s] * scale);
        }
        __syncthreads();

        // ---- MFMA: 5 taps x 4 ntiles x 4 mtiles, K=32 per chunk ----
        const int dh[5] = {-1, 0, 0, 0, 1};
        const int dw[5] = { 0,-1, 0, 1, 0};
        #pragma unroll
        for (int s = 0; s < 5; ++s) {
            int xrow = wid + 1 + dh[s];
            int xcb  = l15 + 1 + dw[s];
            v8s af[4];
            #pragma unroll
            for (int mt = 0; mt < 4; ++mt)
                af[mt] = *(const v8s*)&wlds[(((s * 4 + mt) * 4 + quad) * 16 + l15) * 8];
            #pragma unroll
            for (int nt = 0; nt < 4; ++nt) {
                v4i bi;
                #pragma unroll
                for (int p = 0; p < 4; ++p)
                    bi[p] = xs4[(quad * 4 + p) * 412 + xrow * 68 + nt * 16 + xcb];
                v8s bfr = __builtin_bit_cast(v8s, bi);
                #pragma unroll
                for (int mt = 0; mt < 4; ++mt)
                    acc[mt][nt] = __builtin_amdgcn_mfma_f32_16x16x32_bf16(
                        af[mt], bfr, acc[mt][nt], 0, 0, 0);
            }
        }
        __syncthreads();
    }

    // ---- epilogue: C/D layout col=lane&15 (spatial), row=quad*4+reg (o) ----
    #pragma unroll
    for (int mt = 0; mt < 4; ++mt) {
        #pragma unroll
        for (int nt = 0; nt < 4; ++nt) {
            #pragma unroll
            for (int r = 0; r < 4; ++r) {
                int o = oBase + mt * 16 + quad * 4 + r;
                int c = c0 + nt * 16 + l15;
                out[((size_t)(b * CO + o) * HH + row) * WW + c] = acc[mt][nt][r];
            }
        }
    }
}

extern "C" void kernel_launch(void* const* d_in, const int* in_sizes, int n_in,
                              void* d_out, int out_size, void* d_ws, size_t ws_size,
                              hipStream_t stream) {
    const float* x   = (const float*)d_in[0];
    const float* y   = (const float*)d_in[1];
    const float* wgt = (const float*)d_in[2];
    // d_in[3] = stencil_index, constant [1,3,4,5,7] -> taps hardcoded above.
    float* out  = (float*)d_out;
    float* dbuf = (float*)d_ws;          // needs BS*CO*4 = 8 KB scratch

    demod_kernel<<<dim3(BS * CO), dim3(256), 0, stream>>>(y, wgt, dbuf);
    conv_kernel<<<dim3(64, CO / 64, BS), dim3(256), 0, stream>>>(x, y, wgt, dbuf, out);
}

// Round 2
// 399.625 us; speedup vs baseline: 1.4400x; 1.4400x over previous
//
#include <hip/hip_runtime.h>

// LatticeStyleConv: StyleGAN2-modulated 5-point stencil conv as implicit GEMM
// on bf16 MFMA (16x16x32). bs=8, ci=co=256, H=W=128.
//
// R2 structure:
//   demod_kernel: d[b][o] = rsqrt(sum (w*(y+1))^2 + eps)          -> ws[0..8KB)
//   wprep_kernel: modulated bf16 weights in A-frag-native layout  -> ws[8KB..)
//                 [b][ot][ck][s][mt][quad][m=16][j=8]
//   conv_kernel:  A-frags straight from global (L2), x staged in LDS
//                 pixel-major 32ch contiguous (px stride 80B) so a B-frag is
//                 ONE ds_read_b128 (bank-uniform). Interior staging float4x2ch
//                 -> 4 packed ds_write_b32 (2-way, free). No weight LDS.
// Verified layouts (guide §3 m89/m91): A[m=lane&15][k=quad*8+j];
// B[n=lane&15][k=quad*8+j]; C/D col=lane&15, row=quad*4+reg.

typedef short v8s __attribute__((ext_vector_type(8)));
typedef float v4f __attribute__((ext_vector_type(4)));
typedef int   v4i __attribute__((ext_vector_type(4)));

#define BS 8
#define CI 256
#define CO 256
#define HH 128
#define WW 128

// halfwords per (b,ot,ck) A-frag slab: 5 taps * 4 mt * 4 quad * 16 m * 8 j
#define WF_CK 10240
#define PXS 20   // ints per pixel in LDS: 16 used (32ch bf16) + 4 pad (banking)

__device__ __forceinline__ unsigned short f2bf(float f) {
    unsigned u = __builtin_bit_cast(unsigned, f);
    u += 0x7FFFu + ((u >> 16) & 1u);   // RNE (inputs finite)
    return (unsigned short)(u >> 16);
}

// ---------------- Kernel 1: demodulation factors ----------------
__global__ __launch_bounds__(256) void demod_kernel(const float* __restrict__ y,
                                                    const float* __restrict__ wgt,
                                                    float* __restrict__ dbuf) {
    const int bo = blockIdx.x;           // b*256 + o
    const int b = bo >> 8, o = bo & 255;
    const int i = threadIdx.x;           // one ci per thread
    const float* wp = wgt + (o * CI + i) * 5;
    const float ym = y[b * CI + i] + 1.0f;
    float s2 = 0.f;
    #pragma unroll
    for (int s = 0; s < 5; ++s) { float w = wp[s]; s2 += w * w; }
    float val = ym * ym * s2;
    #pragma unroll
    for (int off = 32; off > 0; off >>= 1) val += __shfl_down(val, off);
    __shared__ float red[4];
    if ((threadIdx.x & 63) == 0) red[threadIdx.x >> 6] = val;
    __syncthreads();
    if (threadIdx.x == 0) {
        float t = red[0] + red[1] + red[2] + red[3];
        dbuf[bo] = rsqrtf(t + 1e-6f);
    }
}

// ---------------- Kernel 2: modulated weights -> A-frag layout ----------------
__global__ __launch_bounds__(256) void wprep_kernel(const float* __restrict__ y,
                                                    const float* __restrict__ wgt,
                                                    const float* __restrict__ dbuf,
                                                    short* __restrict__ wfrag) {
    const int bo = blockIdx.x;
    const int b = bo >> 8, o = bo & 255;
    const int ci = threadIdx.x;
    const float scale = (y[b * CI + ci] + 1.0f) * dbuf[bo];
    const float* wp = wgt + (o * CI + ci) * 5;
    const int ot = o >> 6, mt = (o >> 4) & 3, m = o & 15;
    const int ck = ci >> 5, quad = (ci >> 3) & 3, j = ci & 7;
    size_t base = ((size_t)(b * 4 + ot) * 8 + ck) * WF_CK + quad * 128 + m * 8 + j;
    #pragma unroll
    for (int s = 0; s < 5; ++s)
        wfrag[base + (size_t)(s * 4 + mt) * 512] = (short)f2bf(wp[s] * scale);
}

// ---------------- Kernel 3: conv (MFMA, A from global, x via LDS) ----------------
__global__ __launch_bounds__(256, 4) void conv_kernel(const float* __restrict__ x,
                                                      const short* __restrict__ wfrag,
                                                      float* __restrict__ out) {
    const int b     = blockIdx.z;
    const int ot    = blockIdx.y;
    const int oBase = ot * 64;
    const int st    = blockIdx.x;        // 0..63: 32 row-tiles x 2 col-tiles
    const int r0    = (st >> 1) * 4;
    const int c0    = (st & 1) * 64;

    const int tid  = threadIdx.x;
    const int wid  = tid >> 6;           // wave id 0..3 -> output row r0+wid
    const int lane = tid & 63;
    const int l15  = lane & 15;
    const int quad = lane >> 4;

    // x tile: 6 rows x 66 cols, pixel-major, 32 channels bf16 contiguous.
    // px stride 20 ints (80 B): b128 reads hit every bank exactly 8x.
    __shared__ __align__(16) int xs[6 * 66 * PXS];   // 31680 B

    v4f acc[4][4];
    #pragma unroll
    for (int a = 0; a < 4; ++a)
        #pragma unroll
        for (int n = 0; n < 4; ++n) acc[a][n] = (v4f){0.f, 0.f, 0.f, 0.f};

    const int row = r0 + wid;
    const short* wfb = wfrag + (size_t)(b * 4 + ot) * 8 * WF_CK;

    const int dh[5] = {-1, 0, 0, 0, 1};
    const int dw[5] = { 0,-1, 0, 1, 0};

    for (int ck = 0; ck < 8; ++ck) {
        const int ic0 = ck * 32;
        // ---- interior staging: 16cp x 6rr x 16cq = 1536 iters, 6/thread ----
        #pragma unroll
        for (int t = 0; t < 6; ++t) {
            int idx = tid + t * 256;
            int cp  = idx & 15;
            int tmp = idx >> 4;
            int cq  = tmp & 15;
            int rr  = tmp >> 4;          // 0..5
            int gr  = r0 - 1 + rr;
            v4f a0 = (v4f){0.f, 0.f, 0.f, 0.f}, a1 = a0;
            if (gr >= 0 && gr < HH) {
                const float* xp = x + ((size_t)(b * CI + ic0 + cp * 2) * HH + gr) * WW
                                    + (c0 + cq * 4);
                a0 = *(const v4f*)xp;
                a1 = *(const v4f*)(xp + HH * WW);
            }
            int base = (rr * 66 + cq * 4 + 1) * PXS + cp;
            #pragma unroll
            for (int k = 0; k < 4; ++k)
                xs[base + k * PXS] =
                    (int)((unsigned)f2bf(a0[k]) | ((unsigned)f2bf(a1[k]) << 16));
        }
        // ---- halo staging: cols 0 and 65, 2 x 6rr x 16cp = 192 ints ----
        if (tid < 192) {
            int cp   = tid & 15;
            int tmp  = tid >> 4;         // 0..11
            int side = (tmp >= 6) ? 1 : 0;
            int rr   = tmp - 6 * side;
            int gr   = r0 - 1 + rr;
            int gc   = side ? (c0 + 64) : (c0 - 1);
            float v0 = 0.f, v1 = 0.f;
            if (gr >= 0 && gr < HH && gc >= 0 && gc < WW) {
                const float* xp = x + ((size_t)(b * CI + ic0 + cp * 2) * HH + gr) * WW + gc;
                v0 = xp[0];
                v1 = xp[HH * WW];
            }
            int col = side ? 65 : 0;
            xs[(rr * 66 + col) * PXS + cp] =
                (int)((unsigned)f2bf(v0) | ((unsigned)f2bf(v1) << 16));
        }
        __syncthreads();

        // ---- MFMA: per tap, A-frags from global (L2), B-frag = 1 ds_read_b128
        const short* wfc = wfb + (size_t)ck * WF_CK;
        #pragma unroll
        for (int s = 0; s < 5; ++s) {
            const int xrow = wid + 1 + dh[s];
            const int xc0  = 1 + dw[s];
            v8s af[4];
            #pragma unroll
            for (int mt = 0; mt < 4; ++mt)
                af[mt] = *(const v8s*)(wfc + (size_t)((s * 4 + mt) * 4 + quad) * 128
                                           + l15 * 8);
            #pragma unroll
            for (int nt = 0; nt < 4; ++nt) {
                int px = xrow * 66 + nt * 16 + l15 + xc0;
                v4i bi = *(const v4i*)&xs[px * PXS + quad * 4];
                v8s bfr = __builtin_bit_cast(v8s, bi);
                #pragma unroll
                for (int mt = 0; mt < 4; ++mt)
                    acc[mt][nt] = __builtin_amdgcn_mfma_f32_16x16x32_bf16(
                        af[mt], bfr, acc[mt][nt], 0, 0, 0);
            }
        }
        __syncthreads();
    }

    // ---- epilogue: C/D col=lane&15 (spatial), row=quad*4+reg (o) ----
    #pragma unroll
    for (int mt = 0; mt < 4; ++mt) {
        #pragma unroll
        for (int nt = 0; nt < 4; ++nt) {
            #pragma unroll
            for (int r = 0; r < 4; ++r) {
                int o = oBase + mt * 16 + quad * 4 + r;
                int c = c0 + nt * 16 + l15;
                out[((size_t)(b * CO + o) * HH + row) * WW + c] = acc[mt][nt][r];
            }
        }
    }
}

// ================= Fallback (R1 kernel, used if ws too small) =================
__global__ __launch_bounds__(256) void conv_kernel_fb(const float* __restrict__ x,
                                                      const float* __restrict__ y,
                                                      const float* __restrict__ wgt,
                                                      const float* __restrict__ dbuf,
                                                      float* __restrict__ out) {
    const int b     = blockIdx.z;
    const int oBase = blockIdx.y * 64;
    const int st    = blockIdx.x;
    const int r0    = (st >> 1) * 4;
    const int c0    = (st & 1) * 64;
    const int tid  = threadIdx.x;
    const int wid  = tid >> 6;
    const int lane = tid & 63;
    const int l15  = lane & 15;
    const int quad = lane >> 4;
    __shared__ int   xs4[16 * 412];
    __shared__ short wlds[5 * 4 * 4 * 16 * 8];
    v4f acc[4][4];
    #pragma unroll
    for (int a = 0; a < 4; ++a)
        #pragma unroll
        for (int n = 0; n < 4; ++n) acc[a][n] = (v4f){0.f, 0.f, 0.f, 0.f};
    const int row = r0 + wid;
    for (int ic0 = 0; ic0 < CI; ic0 += 32) {
        for (int t = 0; t < 25; ++t) {
            int idx = tid + t * 256;
            if (idx < 6336) {
                int cp  = idx / 396;
                int rem = idx - cp * 396;
                int rr  = rem / 66;
                int cc  = rem - rr * 66;
                int gr  = r0 - 1 + rr;
                int gc  = c0 - 1 + cc;
                float v0 = 0.f, v1 = 0.f;
                if (gr >= 0 && gr < HH && gc >= 0 && gc < WW) {
                    const float* xp = x + ((size_t)(b * CI + ic0 + cp * 2) * HH + gr) * WW + gc;
                    v0 = xp[0];
                    v1 = xp[HH * WW];
                }
                unsigned pk = (unsigned)f2bf(v0) | ((unsigned)f2bf(v1) << 16);
                xs4[cp * 412 + rr * 68 + cc] = (int)pk;
            }
        }
        #pragma unroll
        for (int p = 0; p < 8; ++p) {
            int pidx = tid + p * 256;
            int ol = pidx >> 5;
            int il = pidx & 31;
            int o  = oBase + ol;
            int ci = ic0 + il;
            float scale = (y[b * CI + ci] + 1.0f) * dbuf[b * CO + o];
            const float* wp = wgt + (o * CI + ci) * 5;
            int base = (((ol >> 4) * 4 + (il >> 3)) * 16 + (ol & 15)) * 8 + (il & 7);
            #pragma unroll
            for (int s = 0; s < 5; ++s)
                wlds[base + s * (4 * 4 * 16 * 8)] = (short)f2bf(wp[s] * scale);
        }
        __syncthreads();
        const int dh[5] = {-1, 0, 0, 0, 1};
        const int dw[5] = { 0,-1, 0, 1, 0};
        #pragma unroll
        for (int s = 0; s < 5; ++s) {
            int xrow = wid + 1 + dh[s];
            int xcb  = l15 + 1 + dw[s];
            v8s af[4];
            #pragma unroll
            for (int mt = 0; mt < 4; ++mt)
                af[mt] = *(const v8s*)&wlds[(((s * 4 + mt) * 4 + quad) * 16 + l15) * 8];
            #pragma unroll
            for (int nt = 0; nt < 4; ++nt) {
                v4i bi;
                #pragma unroll
                for (int p = 0; p < 4; ++p)
                    bi[p] = xs4[(quad * 4 + p) * 412 + xrow * 68 + nt * 16 + xcb];
                v8s bfr = __builtin_bit_cast(v8s, bi);
                #pragma unroll
                for (int mt = 0; mt < 4; ++mt)
                    acc[mt][nt] = __builtin_amdgcn_mfma_f32_16x16x32_bf16(
                        af[mt], bfr, acc[mt][nt], 0, 0, 0);
            }
        }
        __syncthreads();
    }
    #pragma unroll
    for (int mt = 0; mt < 4; ++mt)
        #pragma unroll
        for (int nt = 0; nt < 4; ++nt)
            #pragma unroll
            for (int r = 0; r < 4; ++r) {
                int o = oBase + mt * 16 + quad * 4 + r;
                int c = c0 + nt * 16 + l15;
                out[((size_t)(b * CO + o) * HH + row) * WW + c] = acc[mt][nt][r];
            }
}

extern "C" void kernel_launch(void* const* d_in, const int* in_sizes, int n_in,
                              void* d_out, int out_size, void* d_ws, size_t ws_size,
                              hipStream_t stream) {
    const float* x   = (const float*)d_in[0];
    const float* y   = (const float*)d_in[1];
    const float* wgt = (const float*)d_in[2];
    // d_in[3] = stencil_index, constant [1,3,4,5,7] -> taps hardcoded.
    float* out  = (float*)d_out;
    float* dbuf = (float*)d_ws;                       // 8 KB
    short* wfrag = (short*)((char*)d_ws + 8192);      // 5.24 MB A-frag weights

    const size_t NEED = 8192 + (size_t)BS * 4 * 8 * WF_CK * sizeof(short);

    demod_kernel<<<dim3(BS * CO), dim3(256), 0, stream>>>(y, wgt, dbuf);
    if (ws_size >= NEED) {
        wprep_kernel<<<dim3(BS * CO), dim3(256), 0, stream>>>(y, wgt, dbuf, wfrag);
        conv_kernel<<<dim3(64, CO / 64, BS), dim3(256), 0, stream>>>(x, wfrag, out);
    } else {
        conv_kernel_fb<<<dim3(64, CO / 64, BS), dim3(256), 0, stream>>>(x, y, wgt, dbuf, out);
    }
}

// Round 3
// 309.640 us; speedup vs baseline: 1.8584x; 1.2906x over previous
//
#include <hip/hip_runtime.h>

// LatticeStyleConv R3: StyleGAN2-modulated 5-point stencil conv, bf16 MFMA.
// bs=8, ci=co=256, H=W=128.
//
// Full path (ws >= ~72.4 MB):
//   wprep2: demod + modulated bf16 weights in A-frag layout  -> ws wfrag (5.25MB)
//   xprep:  x fp32 [ci][h][w] -> bf16 pixel-major x_t[b][ck][h][w][32ch] (64MB)
//   conv3:  x tile staged via async global_load_lds dwordx4 (contiguous rows!),
//           B-frag = 1 contiguous ds_read_b128 (conflict-free), A-frags from
//           global (L2). Halos: top/bot rows & left col pre-zeroed once (never
//           overwritten); right-edge px masked in registers (s==3,nt==3 only).
// Mid path (ws >= 5.25MB): wprep2 + R2 conv. Min path: R1 conv.
// Layouts (guide §3 m89/m91): A[m=l15][k=quad*8+j]; B[n=l15][k=quad*8+j];
// C/D col=l15, row=quad*4+reg.

typedef short v8s __attribute__((ext_vector_type(8)));
typedef float v4f __attribute__((ext_vector_type(4)));
typedef int   v4i __attribute__((ext_vector_type(4)));

#define BS 8
#define CI 256
#define CO 256
#define HH 128
#define WW 128

#define WF_CK 10240          // shorts per (b,ot,ck) A-frag slab
#define RSTR_B 5632          // conv3 LDS row stride bytes (88 px * 64B)
#define RSTR_I 1408          // ... in ints

#define GLOAD_LDS16(g, l)                                                  \
    __builtin_amdgcn_global_load_lds(                                      \
        (__attribute__((address_space(1))) void*)(g),                      \
        (__attribute__((address_space(3))) void*)(l), 16, 0, 0)

__device__ __forceinline__ unsigned short f2bf(float f) {
    unsigned u = __builtin_bit_cast(unsigned, f);
    u += 0x7FFFu + ((u >> 16) & 1u);   // RNE (inputs finite)
    return (unsigned short)(u >> 16);
}

// -------- wprep2: fused demod + modulated weights -> A-frag global layout ----
__global__ __launch_bounds__(256) void wprep2_kernel(const float* __restrict__ y,
                                                     const float* __restrict__ wgt,
                                                     short* __restrict__ wfrag) {
    const int bo = blockIdx.x;
    const int b = bo >> 8, o = bo & 255;
    const int ci = threadIdx.x;
    const float ym = y[b * CI + ci] + 1.0f;
    const float* wp = wgt + (o * CI + ci) * 5;
    float w[5];
    float s2 = 0.f;
    #pragma unroll
    for (int s = 0; s < 5; ++s) { w[s] = wp[s]; s2 += w[s] * w[s]; }
    float ss = ym * ym * s2;
    #pragma unroll
    for (int off = 32; off > 0; off >>= 1) ss += __shfl_down(ss, off);
    __shared__ float red[4];
    if ((threadIdx.x & 63) == 0) red[threadIdx.x >> 6] = ss;
    __syncthreads();
    const float tot = red[0] + red[1] + red[2] + red[3];
    const float scale = ym * rsqrtf(tot + 1e-6f);
    const int ot = o >> 6, mt = (o >> 4) & 3, m = o & 15;
    const int ck = ci >> 5, quad = (ci >> 3) & 3, j = ci & 7;
    size_t base = ((size_t)(b * 4 + ot) * 8 + ck) * WF_CK + quad * 128 + m * 8 + j;
    #pragma unroll
    for (int s = 0; s < 5; ++s)
        wfrag[base + (size_t)(s * 4 + mt) * 512] = (short)f2bf(w[s] * scale);
}

// -------- xprep: x fp32 [b][ci][h][w] -> bf16 x_t[b][ck][h][w][32ch] --------
__global__ __launch_bounds__(256) void xprep_kernel(const float* __restrict__ x,
                                                    unsigned int* __restrict__ xt) {
    const int bid = blockIdx.x;            // (b*8 + ck)*128 + h
    const int b  = bid >> 10;
    const int ck = (bid >> 7) & 7;
    const int h  = bid & 127;
    const int tid = threadIdx.x;
    __shared__ float tr[128 * 33];         // [px][c], pad 33 -> conflict-free
    #pragma unroll
    for (int i = 0; i < 16; ++i) {
        int idx = tid + i * 256;
        int c = idx >> 7, px = idx & 127;
        tr[px * 33 + c] = x[((size_t)(b * CI + ck * 32 + c) * HH + h) * WW + px];
    }
    __syncthreads();
    const int px = tid >> 1, half = tid & 1;
    unsigned pk[8];
    #pragma unroll
    for (int k = 0; k < 8; ++k) {
        float f0 = tr[px * 33 + half * 16 + 2 * k];
        float f1 = tr[px * 33 + half * 16 + 2 * k + 1];
        pk[k] = (unsigned)f2bf(f0) | ((unsigned)f2bf(f1) << 16);
    }
    unsigned int* dst = xt + ((size_t)((b * 8 + ck) * 16384 + h * 128 + px)) * 16
                           + half * 8;
    *(v4i*)dst       = (v4i){(int)pk[0], (int)pk[1], (int)pk[2], (int)pk[3]};
    *(v4i*)(dst + 4) = (v4i){(int)pk[4], (int)pk[5], (int)pk[6], (int)pk[7]};
}

// -------- conv3: async-staged x, A from global, MFMA --------
__global__ __launch_bounds__(256, 4) void conv3_kernel(const char* __restrict__ xt,
                                                       const short* __restrict__ wfrag,
                                                       float* __restrict__ out) {
    const int b     = blockIdx.z;
    const int ot    = blockIdx.y;
    const int oBase = ot * 64;
    const int st    = blockIdx.x;          // 32 row-tiles x 2 col-tiles
    const int r0    = (st >> 1) * 4;
    const int c0    = (st & 1) * 64;
    const bool left = (c0 == 0);

    const int tid  = threadIdx.x;
    const int wid  = tid >> 6;
    const int lane = tid & 63;
    const int l15  = lane & 15;
    const int quad = lane >> 4;

    __shared__ __align__(16) int xs[6 * RSTR_I];    // 33792 B

    v4f acc[4][4];
    #pragma unroll
    for (int a = 0; a < 4; ++a)
        #pragma unroll
        for (int n = 0; n < 4; ++n) acc[a][n] = (v4f){0.f, 0.f, 0.f, 0.f};

    // ---- one-time zeroing of never-loaded halo regions ----
    const v4i z4 = (v4i){0, 0, 0, 0};
    if (r0 == 0)
        for (int i = tid; i < 264; i += 256) *(v4i*)&xs[i * 4] = z4;                 // row 0, px0..65
    if (r0 == HH - 4)
        for (int i = tid; i < 264; i += 256) *(v4i*)&xs[5 * RSTR_I + i * 4] = z4;    // row 5
    if (left && tid < 24) *(v4i*)&xs[(tid >> 2) * RSTR_I + (tid & 3) * 4] = z4;      // px0 col
    // first chunk's __syncthreads covers these writes

    const int row = r0 + wid;
    const short* wfb = wfrag + (size_t)(b * 4 + ot) * 8 * WF_CK;
    const bool rz = (!left) && (l15 == 15);          // right-edge gc=128 mask
    const int gstartB = left ? 0 : (c0 - 1) * 64;    // byte offset of first loaded px
    const int lshift  = left ? 64 : 0;

    const int dh[5] = {-1, 0, 0, 0, 1};
    const int dw[5] = { 0,-1, 0, 1, 0};

    for (int ck = 0; ck < 8; ++ck) {
        const char* planep = xt + (((size_t)(b * 8 + ck)) << 20);
        // ---- async staging: rows rr in {wid, wid+4}, 5x1024B per row ----
        #pragma unroll
        for (int rsel = 0; rsel < 2; ++rsel) {
            int rr = wid + rsel * 4;
            if (rr < 6) {
                bool skip = (r0 == 0 && rr == 0) || (r0 == HH - 4 && rr == 5);
                if (!skip) {
                    int gr = r0 - 1 + rr;
                    const char* gb = planep + (size_t)gr * 8192 + gstartB + lane * 16;
                    char* lb = (char*)xs + rr * RSTR_B + lshift;
                    #pragma unroll
                    for (int t = 0; t < 5; ++t)
                        GLOAD_LDS16(gb + t * 1024, lb + t * 1024);
                }
            }
        }
        __syncthreads();   // drains vmcnt: x tile ready

        const short* wfc = wfb + (size_t)ck * WF_CK;
        #pragma unroll
        for (int s = 0; s < 5; ++s) {
            const int xrow = wid + 1 + dh[s];
            const int xc0  = 1 + dw[s];
            v8s af[4];
            #pragma unroll
            for (int mt = 0; mt < 4; ++mt)
                af[mt] = *(const v8s*)(wfc + (size_t)((s * 4 + mt) * 4 + quad) * 128
                                           + l15 * 8);
            #pragma unroll
            for (int nt = 0; nt < 4; ++nt) {
                v4i bi = *(const v4i*)&xs[xrow * RSTR_I + (nt * 16 + l15 + xc0) * 16
                                          + quad * 4];
                if (s == 3 && nt == 3) { if (rz) bi = z4; }   // gc=128 -> 0
                v8s bfr = __builtin_bit_cast(v8s, bi);
                #pragma unroll
                for (int mt = 0; mt < 4; ++mt)
                    acc[mt][nt] = __builtin_amdgcn_mfma_f32_16x16x32_bf16(
                        af[mt], bfr, acc[mt][nt], 0, 0, 0);
            }
        }
        __syncthreads();   // protect xs before next chunk's DMA
    }

    #pragma unroll
    for (int mt = 0; mt < 4; ++mt)
        #pragma unroll
        for (int nt = 0; nt < 4; ++nt)
            #pragma unroll
            for (int r = 0; r < 4; ++r) {
                int o = oBase + mt * 16 + quad * 4 + r;
                int c = c0 + nt * 16 + l15;
                out[((size_t)(b * CO + o) * HH + row) * WW + c] = acc[mt][nt][r];
            }
}

// ================= R2 conv (mid fallback) =================
__global__ __launch_bounds__(256, 4) void conv_kernel(const float* __restrict__ x,
                                                      const short* __restrict__ wfrag,
                                                      float* __restrict__ out) {
    const int b     = blockIdx.z;
    const int ot    = blockIdx.y;
    const int oBase = ot * 64;
    const int st    = blockIdx.x;
    const int r0    = (st >> 1) * 4;
    const int c0    = (st & 1) * 64;
    const int tid  = threadIdx.x;
    const int wid  = tid >> 6;
    const int lane = tid & 63;
    const int l15  = lane & 15;
    const int quad = lane >> 4;
    #define PXS 20
    __shared__ __align__(16) int xs[6 * 66 * PXS];
    v4f acc[4][4];
    #pragma unroll
    for (int a = 0; a < 4; ++a)
        #pragma unroll
        for (int n = 0; n < 4; ++n) acc[a][n] = (v4f){0.f, 0.f, 0.f, 0.f};
    const int row = r0 + wid;
    const short* wfb = wfrag + (size_t)(b * 4 + ot) * 8 * WF_CK;
    const int dh[5] = {-1, 0, 0, 0, 1};
    const int dw[5] = { 0,-1, 0, 1, 0};
    for (int ck = 0; ck < 8; ++ck) {
        const int ic0 = ck * 32;
        #pragma unroll
        for (int t = 0; t < 6; ++t) {
            int idx = tid + t * 256;
            int cp  = idx & 15;
            int tmp = idx >> 4;
            int cq  = tmp & 15;
            int rr  = tmp >> 4;
            int gr  = r0 - 1 + rr;
            v4f a0 = (v4f){0.f, 0.f, 0.f, 0.f}, a1 = a0;
            if (gr >= 0 && gr < HH) {
                const float* xp = x + ((size_t)(b * CI + ic0 + cp * 2) * HH + gr) * WW
                                    + (c0 + cq * 4);
                a0 = *(const v4f*)xp;
                a1 = *(const v4f*)(xp + HH * WW);
            }
            int base = (rr * 66 + cq * 4 + 1) * PXS + cp;
            #pragma unroll
            for (int k = 0; k < 4; ++k)
                xs[base + k * PXS] =
                    (int)((unsigned)f2bf(a0[k]) | ((unsigned)f2bf(a1[k]) << 16));
        }
        if (tid < 192) {
            int cp   = tid & 15;
            int tmp  = tid >> 4;
            int side = (tmp >= 6) ? 1 : 0;
            int rr   = tmp - 6 * side;
            int gr   = r0 - 1 + rr;
            int gc   = side ? (c0 + 64) : (c0 - 1);
            float v0 = 0.f, v1 = 0.f;
            if (gr >= 0 && gr < HH && gc >= 0 && gc < WW) {
                const float* xp = x + ((size_t)(b * CI + ic0 + cp * 2) * HH + gr) * WW + gc;
                v0 = xp[0];
                v1 = xp[HH * WW];
            }
            int col = side ? 65 : 0;
            xs[(rr * 66 + col) * PXS + cp] =
                (int)((unsigned)f2bf(v0) | ((unsigned)f2bf(v1) << 16));
        }
        __syncthreads();
        const short* wfc = wfb + (size_t)ck * WF_CK;
        #pragma unroll
        for (int s = 0; s < 5; ++s) {
            const int xrow = wid + 1 + dh[s];
            const int xc0  = 1 + dw[s];
            v8s af[4];
            #pragma unroll
            for (int mt = 0; mt < 4; ++mt)
                af[mt] = *(const v8s*)(wfc + (size_t)((s * 4 + mt) * 4 + quad) * 128
                                           + l15 * 8);
            #pragma unroll
            for (int nt = 0; nt < 4; ++nt) {
                int px = xrow * 66 + nt * 16 + l15 + xc0;
                v4i bi = *(const v4i*)&xs[px * PXS + quad * 4];
                v8s bfr = __builtin_bit_cast(v8s, bi);
                #pragma unroll
                for (int mt = 0; mt < 4; ++mt)
                    acc[mt][nt] = __builtin_amdgcn_mfma_f32_16x16x32_bf16(
                        af[mt], bfr, acc[mt][nt], 0, 0, 0);
            }
        }
        __syncthreads();
    }
    #pragma unroll
    for (int mt = 0; mt < 4; ++mt)
        #pragma unroll
        for (int nt = 0; nt < 4; ++nt)
            #pragma unroll
            for (int r = 0; r < 4; ++r) {
                int o = oBase + mt * 16 + quad * 4 + r;
                int c = c0 + nt * 16 + l15;
                out[((size_t)(b * CO + o) * HH + row) * WW + c] = acc[mt][nt][r];
            }
}

// ================= R1 min fallback =================
__global__ __launch_bounds__(256) void demod_kernel(const float* __restrict__ y,
                                                    const float* __restrict__ wgt,
                                                    float* __restrict__ dbuf) {
    const int bo = blockIdx.x;
    const int b = bo >> 8, o = bo & 255;
    const int i = threadIdx.x;
    const float* wp = wgt + (o * CI + i) * 5;
    const float ym = y[b * CI + i] + 1.0f;
    float s2 = 0.f;
    #pragma unroll
    for (int s = 0; s < 5; ++s) { float w = wp[s]; s2 += w * w; }
    float val = ym * ym * s2;
    #pragma unroll
    for (int off = 32; off > 0; off >>= 1) val += __shfl_down(val, off);
    __shared__ float red[4];
    if ((threadIdx.x & 63) == 0) red[threadIdx.x >> 6] = val;
    __syncthreads();
    if (threadIdx.x == 0) dbuf[bo] = rsqrtf(red[0] + red[1] + red[2] + red[3] + 1e-6f);
}

__global__ __launch_bounds__(256) void conv_kernel_fb(const float* __restrict__ x,
                                                      const float* __restrict__ y,
                                                      const float* __restrict__ wgt,
                                                      const float* __restrict__ dbuf,
                                                      float* __restrict__ out) {
    const int b     = blockIdx.z;
    const int oBase = blockIdx.y * 64;
    const int st    = blockIdx.x;
    const int r0    = (st >> 1) * 4;
    const int c0    = (st & 1) * 64;
    const int tid  = threadIdx.x;
    const int wid  = tid >> 6;
    const int lane = tid & 63;
    const int l15  = lane & 15;
    const int quad = lane >> 4;
    __shared__ int   xs4[16 * 412];
    __shared__ short wlds[5 * 4 * 4 * 16 * 8];
    v4f acc[4][4];
    #pragma unroll
    for (int a = 0; a < 4; ++a)
        #pragma unroll
        for (int n = 0; n < 4; ++n) acc[a][n] = (v4f){0.f, 0.f, 0.f, 0.f};
    const int row = r0 + wid;
    for (int ic0 = 0; ic0 < CI; ic0 += 32) {
        for (int t = 0; t < 25; ++t) {
            int idx = tid + t * 256;
            if (idx < 6336) {
                int cp  = idx / 396;
                int rem = idx - cp * 396;
                int rr  = rem / 66;
                int cc  = rem - rr * 66;
                int gr  = r0 - 1 + rr;
                int gc  = c0 - 1 + cc;
                float v0 = 0.f, v1 = 0.f;
                if (gr >= 0 && gr < HH && gc >= 0 && gc < WW) {
                    const float* xp = x + ((size_t)(b * CI + ic0 + cp * 2) * HH + gr) * WW + gc;
                    v0 = xp[0];
                    v1 = xp[HH * WW];
                }
                xs4[cp * 412 + rr * 68 + cc] =
                    (int)((unsigned)f2bf(v0) | ((unsigned)f2bf(v1) << 16));
            }
        }
        #pragma unroll
        for (int p = 0; p < 8; ++p) {
            int pidx = tid + p * 256;
            int ol = pidx >> 5;
            int il = pidx & 31;
            int o  = oBase + ol;
            int ci = ic0 + il;
            float scale = (y[b * CI + ci] + 1.0f) * dbuf[b * CO + o];
            const float* wp = wgt + (o * CI + ci) * 5;
            int base = (((ol >> 4) * 4 + (il >> 3)) * 16 + (ol & 15)) * 8 + (il & 7);
            #pragma unroll
            for (int s = 0; s < 5; ++s)
                wlds[base + s * (4 * 4 * 16 * 8)] = (short)f2bf(wp[s] * scale);
        }
        __syncthreads();
        const int dh[5] = {-1, 0, 0, 0, 1};
        const int dw[5] = { 0,-1, 0, 1, 0};
        #pragma unroll
        for (int s = 0; s < 5; ++s) {
            int xrow = wid + 1 + dh[s];
            int xcb  = l15 + 1 + dw[s];
            v8s af[4];
            #pragma unroll
            for (int mt = 0; mt < 4; ++mt)
                af[mt] = *(const v8s*)&wlds[(((s * 4 + mt) * 4 + quad) * 16 + l15) * 8];
            #pragma unroll
            for (int nt = 0; nt < 4; ++nt) {
                v4i bi;
                #pragma unroll
                for (int p = 0; p < 4; ++p)
                    bi[p] = xs4[(quad * 4 + p) * 412 + xrow * 68 + nt * 16 + xcb];
                v8s bfr = __builtin_bit_cast(v8s, bi);
                #pragma unroll
                for (int mt = 0; mt < 4; ++mt)
                    acc[mt][nt] = __builtin_amdgcn_mfma_f32_16x16x32_bf16(
                        af[mt], bfr, acc[mt][nt], 0, 0, 0);
            }
        }
        __syncthreads();
    }
    #pragma unroll
    for (int mt = 0; mt < 4; ++mt)
        #pragma unroll
        for (int nt = 0; nt < 4; ++nt)
            #pragma unroll
            for (int r = 0; r < 4; ++r) {
                int o = oBase + mt * 16 + quad * 4 + r;
                int c = c0 + nt * 16 + l15;
                out[((size_t)(b * CO + o) * HH + row) * WW + c] = acc[mt][nt][r];
            }
}

extern "C" void kernel_launch(void* const* d_in, const int* in_sizes, int n_in,
                              void* d_out, int out_size, void* d_ws, size_t ws_size,
                              hipStream_t stream) {
    const float* x   = (const float*)d_in[0];
    const float* y   = (const float*)d_in[1];
    const float* wgt = (const float*)d_in[2];
    float* out = (float*)d_out;

    const size_t WF_BYTES = (size_t)BS * 4 * 8 * WF_CK * sizeof(short);  // 5.25 MB
    const size_t XT_OFF   = WF_BYTES + 8192;
    const size_t XT_BYTES = (size_t)BS * 8 * 16384 * 64;                 // 64 MB
    const size_t NEED_FULL = XT_OFF + XT_BYTES + 1024;                   // OOB slack
    const size_t NEED_MID  = WF_BYTES + 8192;

    short* wfrag = (short*)d_ws;

    if (ws_size >= NEED_FULL) {
        unsigned int* xt = (unsigned int*)((char*)d_ws + XT_OFF);
        wprep2_kernel<<<dim3(BS * CO), dim3(256), 0, stream>>>(y, wgt, wfrag);
        xprep_kernel<<<dim3(BS * 8 * HH), dim3(256), 0, stream>>>(x, xt);
        conv3_kernel<<<dim3(64, CO / 64, BS), dim3(256), 0, stream>>>(
            (const char*)xt, wfrag, out);
    } else if (ws_size >= NEED_MID) {
        wprep2_kernel<<<dim3(BS * CO), dim3(256), 0, stream>>>(y, wgt, wfrag);
        conv_kernel<<<dim3(64, CO / 64, BS), dim3(256), 0, stream>>>(x, wfrag, out);
    } else {
        float* dbuf = (float*)d_ws;   // 8 KB
        demod_kernel<<<dim3(BS * CO), dim3(256), 0, stream>>>(y, wgt, dbuf);
        conv_kernel_fb<<<dim3(64, CO / 64, BS), dim3(256), 0, stream>>>(x, y, wgt, dbuf, out);
    }
}